// Round 4
// baseline (441.509 us; speedup 1.0000x reference)
//
#include <hip/hip_runtime.h>

typedef unsigned short u16;
typedef __attribute__((ext_vector_type(8))) short bf16x8;
typedef __attribute__((ext_vector_type(4))) float f32x4;

#define MFMA16(a, b, c) __builtin_amdgcn_mfma_f32_16x16x32_bf16(a, b, c, 0, 0, 0)

__device__ __forceinline__ u16 f2bf(float f) {
  union { float f; unsigned u; } v; v.f = f;
  unsigned r = v.u + 0x7fffu + ((v.u >> 16) & 1u);
  return (u16)(r >> 16);
}

__device__ __forceinline__ unsigned pkbf(float lo, float hi) {
  unsigned r;
  asm("v_cvt_pk_bf16_f32 %0, %1, %2" : "=v"(r) : "v"(lo), "v"(hi));
  return r;
}

// In-register transpose (verified r2/r3): input a[t][r] = M[t*16 + g*4 + r][li] (f32,
// C-layout of a 32x16 block); output frag: lane holds bf16 M[g*8+j][li] — i.e. the
// MFMA operand for M^T (d-dim = M's 16 cols, k-dim = M's 32 rows).
__device__ __forceinline__ bf16x8 xform(const float* a0, const float* a1, int srcA, bool hi) {
  unsigned p0 = pkbf(a0[0], a0[1]), p1 = pkbf(a0[2], a0[3]);
  unsigned p2 = pkbf(a1[0], a1[1]), p3 = pkbf(a1[2], a1[3]);
  int srcB = srcA + 16;
  unsigned u0 = __shfl((int)p0, srcA), u1 = __shfl((int)p1, srcA);
  unsigned u2 = __shfl((int)p2, srcA), u3 = __shfl((int)p3, srcA);
  unsigned v0 = __shfl((int)p0, srcB), v1 = __shfl((int)p1, srcB);
  unsigned v2 = __shfl((int)p2, srcB), v3 = __shfl((int)p3, srcB);
  union { bf16x8 v; unsigned w[4]; } o;
  o.w[0] = hi ? u2 : u0; o.w[1] = hi ? u3 : u1;
  o.w[2] = hi ? v2 : v0; o.w[3] = hi ? v3 : v1;
  return o.v;
}

// ---------------- pack: weights -> bf16 fragment layout, bias -> per-lane frag order ----
__global__ void pack_kernel(const float* __restrict__ wqkv_w,
                            const float* __restrict__ wp_w,
                            const float* __restrict__ bias_table,
                            u16* __restrict__ wpack, u16* __restrict__ wppack,
                            float* __restrict__ biasf) {
  int i = blockIdx.x * 256 + threadIdx.x;
  if (i < 110592) {
    int j = i & 7, l = (i >> 3) & 63;
    int rest = i >> 9;
    int ks = rest % 6, nt = rest / 6;
    int k = ks * 32 + (l >> 4) * 8 + j;
    int n = nt * 16 + (l & 15);
    wpack[i] = f2bf(wqkv_w[k * 576 + n]);
  } else if (i < 147456) {
    int i2 = i - 110592;
    int j = i2 & 7, l = (i2 >> 3) & 63;
    int rest = i2 >> 9;
    int ks = rest % 6, nt = rest / 6;
    int k = ks * 32 + (l >> 4) * 8 + j;
    int n = nt * 16 + (l & 15);
    wppack[i2] = f2bf(wp_w[k * 192 + n]);
  } else if (i < 172032) {
    int i2 = i - 147456;            // 0..24575
    int r = i2 & 3, lane = (i2 >> 2) & 63, mt = (i2 >> 8) & 3, nt = (i2 >> 10) & 3, h = i2 >> 12;
    int q = nt * 16 + (lane & 15);
    int kk = mt * 16 + (lane >> 4) * 4 + r;
    int idx = ((q >> 3) - (kk >> 3) + 7) * 15 + ((q & 7) - (kk & 7) + 7);
    biasf[i2] = bias_table[idx * 6 + h];
  }
}

// ---------------- fully fused: x -> qkv -> attention -> projection -> out ----------------
// 1 block = 1 window (64 tokens); 6 waves = 6 heads.
// LDS (aliased): phase A: frag buffer [4mt][6ks][64 lane][8] bf16 (24576 B)
//                phase B: osh [64 tok][196] f32 (50176 B)  -> 3 blocks/CU
__global__ __launch_bounds__(384, 4) void win_attn(
    const float* __restrict__ x, const u16* __restrict__ wpack,
    const float* __restrict__ wqkv_b, const float* __restrict__ biasf,
    const u16* __restrict__ wppack, const float* __restrict__ wp_b,
    float* __restrict__ out) {
  __shared__ __align__(16) float ldsf[12544];   // 50176 B
  u16* lds16 = (u16*)ldsf;
  const int tid = threadIdx.x;
  const int lane = tid & 63;
  const int wv = tid >> 6;           // head
  const int g = lane >> 4, li = lane & 15;
  const int blk = blockIdx.x;
  const int bb = blk / 576, rem = blk % 576, wy = rem / 24, wx = rem % 24;
  const size_t xbase = (size_t)bb * 36864;

  // ---- stage x window into LDS as bf16 A-fragments (lane-linear stores) ----
  {
    const int part = tid >> 6, li0 = tid & 15;
    const int rr = li0 >> 3, cc = li0 & 7;
    const float* gp = x + (xbase + (wy * 8 + rr) * 192 + wx * 8 + cc) * 192
                      + part * 32 + ((tid >> 4) & 3) * 8;
    u16* dst = lds16 + tid * 8;
#pragma unroll
    for (int m = 0; m < 4; ++m) {
      float4 f0 = *(const float4*)gp;
      float4 f1 = *(const float4*)(gp + 4);
      union { bf16x8 v; unsigned w[4]; } o;
      o.w[0] = pkbf(f0.x, f0.y); o.w[1] = pkbf(f0.z, f0.w);
      o.w[2] = pkbf(f1.x, f1.y); o.w[3] = pkbf(f1.z, f1.w);
      *(bf16x8*)dst = o.v;
      gp += 73728;                   // +16 tokens = +2 pixel rows
      dst += 3072;
    }
  }
  __syncthreads();

  const float scale = 0.17677669529663687f;   // 1/sqrt(32)
  const f32x4 zero4 = {0.f, 0.f, 0.f, 0.f};
  const int srcA = (lane & 16) * 2 + li;
  const bool hi = lane >= 32;
  const u16* wbase = wpack + lane * 8;

  // ---- Q^T, K^T = mfma(W_frag, x_frag) ----
  f32x4 qt[2][4], kt[2][4];
#pragma unroll
  for (int i = 0; i < 2; ++i)
#pragma unroll
    for (int mt = 0; mt < 4; ++mt) { qt[i][mt] = zero4; kt[i][mt] = zero4; }
#pragma unroll
  for (int ks = 0; ks < 6; ++ks) {
    bf16x8 af[4];
#pragma unroll
    for (int mt = 0; mt < 4; ++mt)
      af[mt] = *(const bf16x8*)(lds16 + ((mt * 6 + ks) * 64 + lane) * 8);
#pragma unroll
    for (int i = 0; i < 2; ++i) {
      bf16x8 wq = *(const bf16x8*)(wbase + ((2 * wv + i) * 6 + ks) * 512);
      bf16x8 wk = *(const bf16x8*)(wbase + ((12 + 2 * wv + i) * 6 + ks) * 512);
#pragma unroll
      for (int mt = 0; mt < 4; ++mt) {
        qt[i][mt] = MFMA16(wq, af[mt], qt[i][mt]);
        kt[i][mt] = MFMA16(wk, af[mt], kt[i][mt]);
      }
    }
  }

  float bqa[2][4], bka[2][4];
#pragma unroll
  for (int i = 0; i < 2; ++i) {
    float4 t1 = *(const float4*)(wqkv_b + wv * 32 + i * 16 + g * 4);
    bqa[i][0] = t1.x; bqa[i][1] = t1.y; bqa[i][2] = t1.z; bqa[i][3] = t1.w;
    float4 t2 = *(const float4*)(wqkv_b + 192 + wv * 32 + i * 16 + g * 4);
    bka[i][0] = t2.x; bka[i][1] = t2.y; bka[i][2] = t2.z; bka[i][3] = t2.w;
  }
  bf16x8 qf[4], kf[4];
#pragma unroll
  for (int mt = 0; mt < 4; ++mt) {
    float a0[4], a1[4];
#pragma unroll
    for (int r = 0; r < 4; ++r) {
      a0[r] = (qt[0][mt][r] + bqa[0][r]) * scale;
      a1[r] = (qt[1][mt][r] + bqa[1][r]) * scale;
    }
    qf[mt] = xform(a0, a1, srcA, hi);
#pragma unroll
    for (int r = 0; r < 4; ++r) {
      a0[r] = kt[0][mt][r] + bka[0][r];
      a1[r] = kt[1][mt][r] + bka[1][r];
    }
    kf[mt] = xform(a0, a1, srcA, hi);
  }

  // ---- V = mfma(x_frag, Wv_frag) ----
  f32x4 va[4][2];
#pragma unroll
  for (int mt = 0; mt < 4; ++mt) { va[mt][0] = zero4; va[mt][1] = zero4; }
#pragma unroll
  for (int ks = 0; ks < 6; ++ks) {
    bf16x8 af[4];
#pragma unroll
    for (int mt = 0; mt < 4; ++mt)
      af[mt] = *(const bf16x8*)(lds16 + ((mt * 6 + ks) * 64 + lane) * 8);
    bf16x8 wv0 = *(const bf16x8*)(wbase + ((24 + 2 * wv) * 6 + ks) * 512);
    bf16x8 wv1 = *(const bf16x8*)(wbase + ((25 + 2 * wv) * 6 + ks) * 512);
#pragma unroll
    for (int mt = 0; mt < 4; ++mt) {
      va[mt][0] = MFMA16(af[mt], wv0, va[mt][0]);
      va[mt][1] = MFMA16(af[mt], wv1, va[mt][1]);
    }
  }
  float bva[2] = { wqkv_b[384 + wv * 32 + li], wqkv_b[384 + wv * 32 + 16 + li] };
  bf16x8 vf[2][2];    // [d-tile i][key-chunk ks2] — doubles as V^T A-operand
#pragma unroll
  for (int i = 0; i < 2; ++i)
#pragma unroll
    for (int ks2 = 0; ks2 < 2; ++ks2) {
      float a0[4], a1[4];
#pragma unroll
      for (int r = 0; r < 4; ++r) {
        a0[r] = va[ks2 * 2][i][r] + bva[i];
        a1[r] = va[ks2 * 2 + 1][i][r] + bva[i];
      }
      vf[i][ks2] = xform(a0, a1, srcA, hi);
    }

  // ---- per-q-tile: S^T = mfma(K,Q), softmax, P-frag, Y^T += V^T P^T ----
  const float* bfh = biasf + (wv * 16) * 256 + lane * 4;
  f32x4 yt[2][4];    // Y^T[ch = i*16+g*4+r][tok = nt*16+li]
#pragma unroll
  for (int nt = 0; nt < 4; ++nt) { yt[0][nt] = zero4; yt[1][nt] = zero4; }
#pragma unroll
  for (int nt = 0; nt < 4; ++nt) {
    f32x4 stn[4];
#pragma unroll
    for (int mt = 0; mt < 4; ++mt) stn[mt] = MFMA16(kf[mt], qf[nt], zero4);
    float e[4][4];
    float mx = -1e30f;
#pragma unroll
    for (int mt = 0; mt < 4; ++mt) {
      float4 b4 = *(const float4*)(bfh + (nt * 4 + mt) * 256);
      e[mt][0] = stn[mt][0] + b4.x;
      e[mt][1] = stn[mt][1] + b4.y;
      e[mt][2] = stn[mt][2] + b4.z;
      e[mt][3] = stn[mt][3] + b4.w;
      mx = fmaxf(mx, fmaxf(fmaxf(e[mt][0], e[mt][1]), fmaxf(e[mt][2], e[mt][3])));
    }
    mx = fmaxf(mx, __shfl_xor(mx, 16));
    mx = fmaxf(mx, __shfl_xor(mx, 32));
    float s = 0.f;
#pragma unroll
    for (int mt = 0; mt < 4; ++mt)
#pragma unroll
      for (int r = 0; r < 4; ++r) { e[mt][r] = __expf(e[mt][r] - mx); s += e[mt][r]; }
    s += __shfl_xor(s, 16);
    s += __shfl_xor(s, 32);
    float inv = 1.0f / s;
#pragma unroll
    for (int ks2 = 0; ks2 < 2; ++ks2) {
      float a0[4], a1[4];
#pragma unroll
      for (int r = 0; r < 4; ++r) {
        a0[r] = e[ks2 * 2][r] * inv;
        a1[r] = e[ks2 * 2 + 1][r] * inv;
      }
      bf16x8 pf = xform(a0, a1, srcA, hi);
      yt[0][nt] = MFMA16(vf[0][ks2], pf, yt[0][nt]);
      yt[1][nt] = MFMA16(vf[1][ks2], pf, yt[1][nt]);
    }
  }

  // ---- Y^T -> proj A-fragments in-register; exchange via LDS (lane-linear) ----
  __syncthreads();   // all xs reads done; reuse frag buffer for Y frags
#pragma unroll
  for (int mt = 0; mt < 4; ++mt) {
    float a0[4], a1[4];
#pragma unroll
    for (int r = 0; r < 4; ++r) { a0[r] = yt[0][mt][r]; a1[r] = yt[1][mt][r]; }
    bf16x8 yfr = xform(a0, a1, srcA, hi);   // Y[tok = li][ch-local = g*8+j] for tile mt
    *(bf16x8*)(lds16 + ((mt * 6 + wv) * 64 + lane) * 8) = yfr;
  }
  __syncthreads();

  // ---- projection: out-tile[mt][och-tile wv*2+j] = sum_ks Y_frag x Wp_frag ----
  f32x4 pacc[4][2];
#pragma unroll
  for (int mt = 0; mt < 4; ++mt) { pacc[mt][0] = zero4; pacc[mt][1] = zero4; }
#pragma unroll
  for (int ks = 0; ks < 6; ++ks) {
    bf16x8 fr[4];
#pragma unroll
    for (int mt = 0; mt < 4; ++mt)
      fr[mt] = *(const bf16x8*)(lds16 + ((mt * 6 + ks) * 64 + lane) * 8);
    bf16x8 bw0 = *(const bf16x8*)(wppack + ((wv * 2) * 6 + ks) * 512 + lane * 8);
    bf16x8 bw1 = *(const bf16x8*)(wppack + ((wv * 2 + 1) * 6 + ks) * 512 + lane * 8);
#pragma unroll
    for (int mt = 0; mt < 4; ++mt) {
      pacc[mt][0] = MFMA16(fr[mt], bw0, pacc[mt][0]);
      pacc[mt][1] = MFMA16(fr[mt], bw1, pacc[mt][1]);
    }
  }
  __syncthreads();   // frag reads done; reuse LDS as osh f32 [64][196]

  // ---- stage out-tile to LDS (2-way banks), then coalesced block copy ----
  {
    const float bb0 = wp_b[wv * 32 + li], bb1 = wp_b[wv * 32 + 16 + li];
#pragma unroll
    for (int mt = 0; mt < 4; ++mt)
#pragma unroll
      for (int r = 0; r < 4; ++r) {
        int tok = mt * 16 + g * 4 + r;
        ldsf[tok * 196 + wv * 32 + li] = pacc[mt][0][r] + bb0;
        ldsf[tok * 196 + wv * 32 + 16 + li] = pacc[mt][1][r] + bb1;
      }
  }
  __syncthreads();
  {
    const int pc = tid / 48, f4q = tid - pc * 48;   // pixel-in-row, float4-in-pixel
#pragma unroll
    for (int pr = 0; pr < 8; ++pr) {
      float4 v = *(const float4*)(ldsf + (pr * 8 + pc) * 196 + f4q * 4);
      *(float4*)(out + (xbase + (wy * 8 + pr) * 192 + wx * 8 + pc) * 192 + f4q * 4) = v;
    }
  }
}

extern "C" void kernel_launch(void* const* d_in, const int* in_sizes, int n_in,
                              void* d_out, int out_size, void* d_ws, size_t ws_size,
                              hipStream_t stream) {
  (void)in_sizes; (void)n_in; (void)out_size; (void)ws_size;
  const float* x          = (const float*)d_in[0];
  const float* wqkv_w     = (const float*)d_in[1];
  const float* wqkv_b     = (const float*)d_in[2];
  const float* wp_w       = (const float*)d_in[3];
  const float* wp_b       = (const float*)d_in[4];
  const float* bias_table = (const float*)d_in[5];
  float* out = (float*)d_out;
  char* ws = (char*)d_ws;
  u16* wpack   = (u16*)(ws);              // 221184 B
  u16* wppack  = (u16*)(ws + 221184);     //  73728 B
  float* biasf = (float*)(ws + 294912);   //  98304 B

  pack_kernel<<<672, 256, 0, stream>>>(wqkv_w, wp_w, bias_table, wpack, wppack, biasf);
  win_attn<<<4608, 384, 0, stream>>>(x, wpack, wqkv_b, biasf, wppack, wp_b, out);
}

// Round 6
// 390.584 us; speedup vs baseline: 1.1304x; 1.1304x over previous
//
#include <hip/hip_runtime.h>
#include <hip/hip_bf16.h>

typedef unsigned short u16;
typedef __attribute__((ext_vector_type(8))) short bf16x8;
typedef __attribute__((ext_vector_type(4))) float f32x4;

#define MFMA16(a, b, c) __builtin_amdgcn_mfma_f32_16x16x32_bf16(a, b, c, 0, 0, 0)

__device__ __forceinline__ u16 f2bf(float f) {
  union { float f; unsigned u; } v; v.f = f;
  unsigned r = v.u + 0x7fffu + ((v.u >> 16) & 1u);
  return (u16)(r >> 16);
}

// Pack two f32 -> packed bf16 pair (lo in bits 0..15). Pure C++ (no inline asm):
// compiler emits its own cvt sequence (m240: scalar-cast codegen >= hand asm).
__device__ __forceinline__ unsigned pkbf(float lo, float hi) {
  union { __hip_bfloat162 h; unsigned u; } v;
  v.h = __hip_bfloat162(__float2bfloat16(lo), __float2bfloat16(hi));
  return v.u;
}

// In-register transpose (verified r2-r4): input a[t][r] = M[t*16 + g*4 + r][li] (f32,
// C-layout of a 32x16 block); output frag: lane holds bf16 M[g*8+j][li] — the MFMA
// operand fragment for M^T.
__device__ __forceinline__ bf16x8 xform(const float* a0, const float* a1, int srcA, bool hi) {
  unsigned p0 = pkbf(a0[0], a0[1]), p1 = pkbf(a0[2], a0[3]);
  unsigned p2 = pkbf(a1[0], a1[1]), p3 = pkbf(a1[2], a1[3]);
  int srcB = srcA + 16;
  unsigned u0 = __shfl((int)p0, srcA), u1 = __shfl((int)p1, srcA);
  unsigned u2 = __shfl((int)p2, srcA), u3 = __shfl((int)p3, srcA);
  unsigned v0 = __shfl((int)p0, srcB), v1 = __shfl((int)p1, srcB);
  unsigned v2 = __shfl((int)p2, srcB), v3 = __shfl((int)p3, srcB);
  union { bf16x8 v; unsigned w[4]; } o;
  o.w[0] = hi ? u2 : u0; o.w[1] = hi ? u3 : u1;
  o.w[2] = hi ? v2 : v0; o.w[3] = hi ? v3 : v1;
  return o.v;
}

// ---------------- pack: weights -> bf16 fragment layout, bias -> per-lane frag order ----
__global__ void pack_kernel(const float* __restrict__ wqkv_w,
                            const float* __restrict__ wp_w,
                            const float* __restrict__ bias_table,
                            u16* __restrict__ wpack, u16* __restrict__ wppack,
                            float* __restrict__ biasf) {
  int i = blockIdx.x * 256 + threadIdx.x;
  if (i < 110592) {
    int j = i & 7, l = (i >> 3) & 63;
    int rest = i >> 9;
    int ks = rest % 6, nt = rest / 6;
    int k = ks * 32 + (l >> 4) * 8 + j;
    int n = nt * 16 + (l & 15);
    wpack[i] = f2bf(wqkv_w[k * 576 + n]);
  } else if (i < 147456) {
    int i2 = i - 110592;
    int j = i2 & 7, l = (i2 >> 3) & 63;
    int rest = i2 >> 9;
    int ks = rest % 6, nt = rest / 6;
    int k = ks * 32 + (l >> 4) * 8 + j;
    int n = nt * 16 + (l & 15);
    wppack[i2] = f2bf(wp_w[k * 192 + n]);
  } else if (i < 172032) {
    int i2 = i - 147456;            // 0..24575
    int r = i2 & 3, lane = (i2 >> 2) & 63, mt = (i2 >> 8) & 3, nt = (i2 >> 10) & 3, h = i2 >> 12;
    int q = nt * 16 + (lane & 15);
    int kk = mt * 16 + (lane >> 4) * 4 + r;
    int idx = ((q >> 3) - (kk >> 3) + 7) * 15 + ((q & 7) - (kk & 7) + 7);
    biasf[i2] = bias_table[idx * 6 + h];
  }
}

// ---------------- fully fused: x -> qkv -> attention -> projection -> out ----------------
// 1 block = 1 window (64 tokens); 6 waves = 6 heads.
// LDS (aliased): phase A: frag buffer [4mt][6ks][64 lane][8] bf16 (24576 B)
//                phase B: osh [64 tok][196] f32 (50176 B)
// __launch_bounds__(384,3): 170-VGPR budget — r4's (384,4) forced 64 VGPR and
// ~690 MB of scratch-spill HBM traffic; the live set (~150 regs) fits 170.
__global__ __launch_bounds__(384, 3) void win_attn(
    const float* __restrict__ x, const u16* __restrict__ wpack,
    const float* __restrict__ wqkv_b, const float* __restrict__ biasf,
    const u16* __restrict__ wppack, const float* __restrict__ wp_b,
    float* __restrict__ out) {
  __shared__ __align__(16) float ldsf[12544];   // 50176 B
  u16* lds16 = (u16*)ldsf;
  const int tid = threadIdx.x;
  const int lane = tid & 63;
  const int wv = tid >> 6;           // head
  const int g = lane >> 4, li = lane & 15;
  const int blk = blockIdx.x;        // no swizzle this round (isolate variables)
  const int bb = blk / 576, rem = blk % 576, wy = rem / 24, wx = rem % 24;
  const size_t xbase = (size_t)bb * 36864;

  // ---- stage x window into LDS as bf16 A-fragments (lane-linear stores) ----
  {
    const int part = tid >> 6, li0 = tid & 15;
    const int rr = li0 >> 3, cc = li0 & 7;
    const float* gp = x + (xbase + (wy * 8 + rr) * 192 + wx * 8 + cc) * 192
                      + part * 32 + ((tid >> 4) & 3) * 8;
    u16* dst = lds16 + tid * 8;
#pragma unroll
    for (int m = 0; m < 4; ++m) {
      float4 f0 = *(const float4*)gp;
      float4 f1 = *(const float4*)(gp + 4);
      union { bf16x8 v; unsigned w[4]; } o;
      o.w[0] = pkbf(f0.x, f0.y); o.w[1] = pkbf(f0.z, f0.w);
      o.w[2] = pkbf(f1.x, f1.y); o.w[3] = pkbf(f1.z, f1.w);
      *(bf16x8*)dst = o.v;
      gp += 73728;                   // +16 tokens = +2 pixel rows
      dst += 3072;
    }
  }
  __syncthreads();

  const float scale = 0.17677669529663687f;   // 1/sqrt(32)
  const f32x4 zero4 = {0.f, 0.f, 0.f, 0.f};
  const int srcA = (lane & 16) * 2 + li;
  const bool hi = lane >= 32;
  const u16* wbase = wpack + lane * 8;

  // ---- Q^T, K^T = mfma(W_frag, x_frag) ----
  f32x4 qt[2][4], kt[2][4];
#pragma unroll
  for (int i = 0; i < 2; ++i)
#pragma unroll
    for (int mt = 0; mt < 4; ++mt) { qt[i][mt] = zero4; kt[i][mt] = zero4; }
#pragma unroll
  for (int ks = 0; ks < 6; ++ks) {
    bf16x8 af[4];
#pragma unroll
    for (int mt = 0; mt < 4; ++mt)
      af[mt] = *(const bf16x8*)(lds16 + ((mt * 6 + ks) * 64 + lane) * 8);
#pragma unroll
    for (int i = 0; i < 2; ++i) {
      bf16x8 wq = *(const bf16x8*)(wbase + ((2 * wv + i) * 6 + ks) * 512);
      bf16x8 wk = *(const bf16x8*)(wbase + ((12 + 2 * wv + i) * 6 + ks) * 512);
#pragma unroll
      for (int mt = 0; mt < 4; ++mt) {
        qt[i][mt] = MFMA16(wq, af[mt], qt[i][mt]);
        kt[i][mt] = MFMA16(wk, af[mt], kt[i][mt]);
      }
    }
  }

  float bqa[2][4], bka[2][4];
#pragma unroll
  for (int i = 0; i < 2; ++i) {
    float4 t1 = *(const float4*)(wqkv_b + wv * 32 + i * 16 + g * 4);
    bqa[i][0] = t1.x; bqa[i][1] = t1.y; bqa[i][2] = t1.z; bqa[i][3] = t1.w;
    float4 t2 = *(const float4*)(wqkv_b + 192 + wv * 32 + i * 16 + g * 4);
    bka[i][0] = t2.x; bka[i][1] = t2.y; bka[i][2] = t2.z; bka[i][3] = t2.w;
  }
  bf16x8 qf[4], kf[4];
#pragma unroll
  for (int mt = 0; mt < 4; ++mt) {
    float a0[4], a1[4];
#pragma unroll
    for (int r = 0; r < 4; ++r) {
      a0[r] = (qt[0][mt][r] + bqa[0][r]) * scale;
      a1[r] = (qt[1][mt][r] + bqa[1][r]) * scale;
    }
    qf[mt] = xform(a0, a1, srcA, hi);
#pragma unroll
    for (int r = 0; r < 4; ++r) {
      a0[r] = kt[0][mt][r] + bka[0][r];
      a1[r] = kt[1][mt][r] + bka[1][r];
    }
    kf[mt] = xform(a0, a1, srcA, hi);
  }

  // ---- V = mfma(x_frag, Wv_frag) ----
  f32x4 va[4][2];
#pragma unroll
  for (int mt = 0; mt < 4; ++mt) { va[mt][0] = zero4; va[mt][1] = zero4; }
#pragma unroll
  for (int ks = 0; ks < 6; ++ks) {
    bf16x8 af[4];
#pragma unroll
    for (int mt = 0; mt < 4; ++mt)
      af[mt] = *(const bf16x8*)(lds16 + ((mt * 6 + ks) * 64 + lane) * 8);
    bf16x8 wv0 = *(const bf16x8*)(wbase + ((24 + 2 * wv) * 6 + ks) * 512);
    bf16x8 wv1 = *(const bf16x8*)(wbase + ((25 + 2 * wv) * 6 + ks) * 512);
#pragma unroll
    for (int mt = 0; mt < 4; ++mt) {
      va[mt][0] = MFMA16(af[mt], wv0, va[mt][0]);
      va[mt][1] = MFMA16(af[mt], wv1, va[mt][1]);
    }
  }
  float bva[2] = { wqkv_b[384 + wv * 32 + li], wqkv_b[384 + wv * 32 + 16 + li] };
  bf16x8 vf[2][2];    // [d-tile i][key-chunk ks2] — V^T A-operand
#pragma unroll
  for (int i = 0; i < 2; ++i)
#pragma unroll
    for (int ks2 = 0; ks2 < 2; ++ks2) {
      float a0[4], a1[4];
#pragma unroll
      for (int r = 0; r < 4; ++r) {
        a0[r] = va[ks2 * 2][i][r] + bva[i];
        a1[r] = va[ks2 * 2 + 1][i][r] + bva[i];
      }
      vf[i][ks2] = xform(a0, a1, srcA, hi);
    }

  // ---- per-q-tile: S^T = mfma(K,Q), softmax, P-frag, Y^T += V^T P^T ----
  const float* bfh = biasf + (wv * 16) * 256 + lane * 4;
  f32x4 yt[2][4];    // Y^T[ch = i*16+g*4+r][tok = nt*16+li]
#pragma unroll
  for (int nt = 0; nt < 4; ++nt) { yt[0][nt] = zero4; yt[1][nt] = zero4; }
#pragma unroll
  for (int nt = 0; nt < 4; ++nt) {
    f32x4 stn[4];
#pragma unroll
    for (int mt = 0; mt < 4; ++mt) stn[mt] = MFMA16(kf[mt], qf[nt], zero4);
    float e[4][4];
    float mx = -1e30f;
#pragma unroll
    for (int mt = 0; mt < 4; ++mt) {
      float4 b4 = *(const float4*)(bfh + (nt * 4 + mt) * 256);
      e[mt][0] = stn[mt][0] + b4.x;
      e[mt][1] = stn[mt][1] + b4.y;
      e[mt][2] = stn[mt][2] + b4.z;
      e[mt][3] = stn[mt][3] + b4.w;
      mx = fmaxf(mx, fmaxf(fmaxf(e[mt][0], e[mt][1]), fmaxf(e[mt][2], e[mt][3])));
    }
    mx = fmaxf(mx, __shfl_xor(mx, 16));
    mx = fmaxf(mx, __shfl_xor(mx, 32));
    float s = 0.f;
#pragma unroll
    for (int mt = 0; mt < 4; ++mt)
#pragma unroll
      for (int r = 0; r < 4; ++r) { e[mt][r] = __expf(e[mt][r] - mx); s += e[mt][r]; }
    s += __shfl_xor(s, 16);
    s += __shfl_xor(s, 32);
    float inv = 1.0f / s;
#pragma unroll
    for (int ks2 = 0; ks2 < 2; ++ks2) {
      float a0[4], a1[4];
#pragma unroll
      for (int r = 0; r < 4; ++r) {
        a0[r] = e[ks2 * 2][r] * inv;
        a1[r] = e[ks2 * 2 + 1][r] * inv;
      }
      bf16x8 pf = xform(a0, a1, srcA, hi);
      yt[0][nt] = MFMA16(vf[0][ks2], pf, yt[0][nt]);
      yt[1][nt] = MFMA16(vf[1][ks2], pf, yt[1][nt]);
    }
  }

  // ---- Y^T -> proj A-fragments in-register; exchange via LDS (lane-linear) ----
  __syncthreads();   // all xs reads done; reuse frag buffer for Y frags
#pragma unroll
  for (int mt = 0; mt < 4; ++mt) {
    float a0[4], a1[4];
#pragma unroll
    for (int r = 0; r < 4; ++r) { a0[r] = yt[0][mt][r]; a1[r] = yt[1][mt][r]; }
    bf16x8 yfr = xform(a0, a1, srcA, hi);   // Y[tok = li][ch-local = g*8+j] for tile mt
    *(bf16x8*)(lds16 + ((mt * 6 + wv) * 64 + lane) * 8) = yfr;
  }
  __syncthreads();

  // ---- projection: out-tile[mt][och-tile wv*2+j] = sum_ks Y_frag x Wp_frag ----
  f32x4 pacc[4][2];
#pragma unroll
  for (int mt = 0; mt < 4; ++mt) { pacc[mt][0] = zero4; pacc[mt][1] = zero4; }
#pragma unroll
  for (int ks = 0; ks < 6; ++ks) {
    bf16x8 fr[4];
#pragma unroll
    for (int mt = 0; mt < 4; ++mt)
      fr[mt] = *(const bf16x8*)(lds16 + ((mt * 6 + ks) * 64 + lane) * 8);
    bf16x8 bw0 = *(const bf16x8*)(wppack + ((wv * 2) * 6 + ks) * 512 + lane * 8);
    bf16x8 bw1 = *(const bf16x8*)(wppack + ((wv * 2 + 1) * 6 + ks) * 512 + lane * 8);
#pragma unroll
    for (int mt = 0; mt < 4; ++mt) {
      pacc[mt][0] = MFMA16(fr[mt], bw0, pacc[mt][0]);
      pacc[mt][1] = MFMA16(fr[mt], bw1, pacc[mt][1]);
    }
  }
  __syncthreads();   // frag reads done; reuse LDS as osh f32 [64][196]

  // ---- stage out-tile to LDS (2-way banks), then coalesced block copy ----
  {
    const float bb0 = wp_b[wv * 32 + li], bb1 = wp_b[wv * 32 + 16 + li];
#pragma unroll
    for (int mt = 0; mt < 4; ++mt)
#pragma unroll
      for (int r = 0; r < 4; ++r) {
        int tok = mt * 16 + g * 4 + r;
        ldsf[tok * 196 + wv * 32 + li] = pacc[mt][0][r] + bb0;
        ldsf[tok * 196 + wv * 32 + 16 + li] = pacc[mt][1][r] + bb1;
      }
  }
  __syncthreads();
  {
    const int pc = tid / 48, f4q = tid - pc * 48;   // pixel-in-row, float4-in-pixel
#pragma unroll
    for (int pr = 0; pr < 8; ++pr) {
      float4 v = *(const float4*)(ldsf + (pr * 8 + pc) * 196 + f4q * 4);
      *(float4*)(out + (xbase + (wy * 8 + pr) * 192 + wx * 8 + pc) * 192 + f4q * 4) = v;
    }
  }
}

extern "C" void kernel_launch(void* const* d_in, const int* in_sizes, int n_in,
                              void* d_out, int out_size, void* d_ws, size_t ws_size,
                              hipStream_t stream) {
  (void)in_sizes; (void)n_in; (void)out_size; (void)ws_size;
  const float* x          = (const float*)d_in[0];
  const float* wqkv_w     = (const float*)d_in[1];
  const float* wqkv_b     = (const float*)d_in[2];
  const float* wp_w       = (const float*)d_in[3];
  const float* wp_b       = (const float*)d_in[4];
  const float* bias_table = (const float*)d_in[5];
  float* out = (float*)d_out;
  char* ws = (char*)d_ws;
  u16* wpack   = (u16*)(ws);              // 221184 B
  u16* wppack  = (u16*)(ws + 221184);     //  73728 B
  float* biasf = (float*)(ws + 294912);   //  98304 B

  pack_kernel<<<672, 256, 0, stream>>>(wqkv_w, wp_w, bias_table, wpack, wppack, biasf);
  win_attn<<<4608, 384, 0, stream>>>(x, wpack, wqkv_b, biasf, wppack, wp_b, out);
}